// Round 4
// baseline (374.848 us; speedup 1.0000x reference)
//
#include <hip/hip_runtime.h>

#define BATCH 2
#define NTOK 256
#define DM 512
#define NH 8
#define HDIM 64

// padded row strides (in ushorts): 4224 B = 33 cache lines; gcd(33,2048)=1
// -> consecutive stream steps sweep all L2 sets (kills 4KB-stride aliasing)
#define PBT_STRIDE (NTOK * 8 + 64)   // 2112 ushorts
#define PVQ_STRIDE (DM * 4 + 64)     // 2112 ushorts

typedef unsigned int uint32;
typedef unsigned short ushort16;

static __device__ __forceinline__ float fast_silu(float x) {
  // x * rcp(1+exp(-x)) : v_exp + v_rcp, no correctly-rounded divide
  return x * __builtin_amdgcn_rcpf(1.0f + __expf(-x));
}
static __device__ __forceinline__ ushort16 bf16_rne(float x) {
  uint32 u = __float_as_uint(x);
  u += 0x7fffu + ((u >> 16) & 1u);
  return (ushort16)(u >> 16);
}
static __device__ __forceinline__ float bf16_lo(uint32 u) {
  return __uint_as_float(u << 16);
}
static __device__ __forceinline__ float bf16_hi(uint32 u) {
  return __uint_as_float(u & 0xffff0000u);
}

// ---------------- prep: per-token MLP1 projections (bf16 packed) + Wb2^T ----------------
// Sb[b,i,d] = Wb1[d,:]*c_i + bb1[d]  (fp32, query side)
// Sv[b,i,d] = Wv1[d,:]*c_i + bv1[d]  (fp32, query side)
// PbT8: bf16, [b][d>>3]{padded}[j][d&7]   (16B per 8 d-elems per j, phase 1b)
// PvQ : bf16, [b][j>>2]{padded}[d][j&3]   (8B per 4 j-elems per d, phase 2)
__global__ __launch_bounds__(256) void prep_pe(
    const float* __restrict__ coords,
    const float* __restrict__ Wb1, const float* __restrict__ bb1,
    const float* __restrict__ Wv1, const float* __restrict__ bv1,
    const float* __restrict__ Wb2,
    float* __restrict__ Sb, float* __restrict__ Sv,
    ushort16* __restrict__ PbT8, ushort16* __restrict__ PvQ,
    float* __restrict__ Wb2T) {
  int idx = blockIdx.x * 256 + threadIdx.x;   // (b,i,d), d fastest
  int d = idx & (DM - 1);
  int i = (idx >> 9) & (NTOK - 1);
  int b = idx >> 17;
  const float* cp = coords + (b * NTOK + i) * 3;
  float c0 = cp[0], c1 = cp[1], c2 = cp[2];
  float pb = Wb1[d * 3 + 0] * c0 + Wb1[d * 3 + 1] * c1 + Wb1[d * 3 + 2] * c2;
  float pv = Wv1[d * 3 + 0] * c0 + Wv1[d * 3 + 1] * c1 + Wv1[d * 3 + 2] * c2;
  Sb[idx] = pb + bb1[d];
  Sv[idx] = pv + bv1[d];
  PbT8[(size_t)(b * 64 + (d >> 3)) * PBT_STRIDE + i * 8 + (d & 7)] = bf16_rne(pb);
  PvQ [(size_t)(b * 64 + (i >> 2)) * PVQ_STRIDE + d * 4 + (i & 3)] = bf16_rne(pv);
  if (idx < DM * NH) {
    int h = idx & 7, dd = idx >> 3;
    Wb2T[idx] = Wb2[h * DM + dd];
  }
}

// ---------------- QKV projection GEMM ----------------
__global__ __launch_bounds__(256) void qkv_gemm(
    const float* __restrict__ X, const float* __restrict__ W,
    const float* __restrict__ bqkv,
    float* __restrict__ Q, float* __restrict__ K, float* __restrict__ V) {
  __shared__ float Xs[64][33];
  __shared__ float Ws[64][33];
  int t = threadIdx.x;
  int bm = blockIdx.x, bn = blockIdx.y;
  int lrow = t >> 2, lk = (t & 3) * 8;
  const float* Xp = X + (bm * 64 + lrow) * DM + lk;
  const float* Wp = W + (bn * 64 + lrow) * DM + lk;
  int tx = t & 15, ty = t >> 4;
  float acc[4][4] = {};
  for (int k0 = 0; k0 < DM; k0 += 32) {
    float4 xa = *(const float4*)(Xp + k0);
    float4 xb = *(const float4*)(Xp + k0 + 4);
    float4 wa = *(const float4*)(Wp + k0);
    float4 wb = *(const float4*)(Wp + k0 + 4);
    __syncthreads();
    Xs[lrow][lk + 0] = xa.x; Xs[lrow][lk + 1] = xa.y;
    Xs[lrow][lk + 2] = xa.z; Xs[lrow][lk + 3] = xa.w;
    Xs[lrow][lk + 4] = xb.x; Xs[lrow][lk + 5] = xb.y;
    Xs[lrow][lk + 6] = xb.z; Xs[lrow][lk + 7] = xb.w;
    Ws[lrow][lk + 0] = wa.x; Ws[lrow][lk + 1] = wa.y;
    Ws[lrow][lk + 2] = wa.z; Ws[lrow][lk + 3] = wa.w;
    Ws[lrow][lk + 4] = wb.x; Ws[lrow][lk + 5] = wb.y;
    Ws[lrow][lk + 6] = wb.z; Ws[lrow][lk + 7] = wb.w;
    __syncthreads();
#pragma unroll
    for (int kk = 0; kk < 32; ++kk) {
      float a0 = Xs[ty * 4 + 0][kk], a1 = Xs[ty * 4 + 1][kk];
      float a2 = Xs[ty * 4 + 2][kk], a3 = Xs[ty * 4 + 3][kk];
      float b0 = Ws[tx * 4 + 0][kk], b1 = Ws[tx * 4 + 1][kk];
      float b2 = Ws[tx * 4 + 2][kk], b3 = Ws[tx * 4 + 3][kk];
      acc[0][0] = fmaf(a0, b0, acc[0][0]); acc[0][1] = fmaf(a0, b1, acc[0][1]);
      acc[0][2] = fmaf(a0, b2, acc[0][2]); acc[0][3] = fmaf(a0, b3, acc[0][3]);
      acc[1][0] = fmaf(a1, b0, acc[1][0]); acc[1][1] = fmaf(a1, b1, acc[1][1]);
      acc[1][2] = fmaf(a1, b2, acc[1][2]); acc[1][3] = fmaf(a1, b3, acc[1][3]);
      acc[2][0] = fmaf(a2, b0, acc[2][0]); acc[2][1] = fmaf(a2, b1, acc[2][1]);
      acc[2][2] = fmaf(a2, b2, acc[2][2]); acc[2][3] = fmaf(a2, b3, acc[2][3]);
      acc[3][0] = fmaf(a3, b0, acc[3][0]); acc[3][1] = fmaf(a3, b1, acc[3][1]);
      acc[3][2] = fmaf(a3, b2, acc[3][2]); acc[3][3] = fmaf(a3, b3, acc[3][3]);
    }
  }
#pragma unroll
  for (int r = 0; r < 4; ++r) {
    int row = bm * 64 + ty * 4 + r;
    int b = row >> 8, i = row & (NTOK - 1);
#pragma unroll
    for (int c = 0; c < 4; ++c) {
      int n = bn * 64 + tx * 4 + c;
      float val = acc[r][c] + bqkv[n];
      if (n < DM) {
        Q[(b * NTOK + i) * DM + n] = val;
      } else if (n < 2 * DM) {
        int u = n - DM; int h = u >> 6, dp = u & 63;
        K[((b * NH + h) * NTOK + i) * HDIM + dp] = val;
      } else {
        int u = n - 2 * DM; int h = u >> 6, dp = u & 63;
        V[((b * NH + h) * NTOK + i) * HDIM + dp] = val;
      }
    }
  }
}

// ---------------- attention part: scores + softmax + g accumulation ----------------
// One block per query. 512 thr = 8 waves. Phase 1: (j = t&255, dh = t>>8) with the
// bias-MLP d-loop split across dh. Phase 2: thread = feature d. Writes softmax
// weights (Wsm[b][i][h][j], contiguous 8KB per block) and g (Gbf, bf16).
__global__ __launch_bounds__(512, 4) void attn_part(
    const float* __restrict__ Q, const float* __restrict__ K,
    const float* __restrict__ Sb, const float* __restrict__ Sv,
    const ushort16* __restrict__ PbT8, const ushort16* __restrict__ PvQ,
    const float* __restrict__ Wb2T,
    float* __restrict__ Wsm, ushort16* __restrict__ Gbf) {
  __shared__ __align__(16) float qL[DM];
  __shared__ __align__(16) float sbL[DM];
  __shared__ __align__(16) float uni[4096];   // 16 KB: red2 (ph1) then sWa/sWb (ph2)
  __shared__ float redm[2][4][4];
  __shared__ float reds[2][4][4];

  int t = threadIdx.x;
  // bijective XCD swizzle: XCD k gets 64 contiguous queries (single batch)
  int blk = ((blockIdx.x & 7) << 6) + (blockIdx.x >> 3);   // b*NTOK + i
  int b = blk >> 8;
  int j = t & (NTOK - 1);
  int dh = t >> 8;
  int dhu = __builtin_amdgcn_readfirstlane(dh);  // wave-uniform -> scalar addressing
  int lane = t & 63;
  int w4 = (t >> 6) & 3;

  qL[t]  = Q [(size_t)blk * DM + t];
  sbL[t] = Sb[(size_t)blk * DM + t];
  __syncthreads();

  // ---- phase 1a: qk for the 4 heads owned by this dh group ----
  float qk[4];
  {
    const float* kb = K + ((size_t)(b * NH + (dhu << 2)) * NTOK + j) * HDIM;
    const float* qb = qL + (dhu << 8);
#pragma unroll
    for (int c = 0; c < 4; ++c) {
      const float* kr = kb + (size_t)c * NTOK * HDIM;
      const float* qr = qb + c * HDIM;
      float acc = 0.f;
#pragma unroll
      for (int dg = 0; dg < HDIM / 4; ++dg) {
        float4 kv = *(const float4*)(kr + dg * 4);
        float4 qv = *(const float4*)(qr + dg * 4);
        acc = fmaf(kv.x, qv.x, acc);
        acc = fmaf(kv.y, qv.y, acc);
        acc = fmaf(kv.z, qv.z, acc);
        acc = fmaf(kv.w, qv.w, acc);
      }
      qk[c] = acc;
    }
  }

  // ---- phase 1b: bias MLP partial over this dh group's 256 d ----
  float bp[NH];
#pragma unroll
  for (int h = 0; h < NH; ++h) bp[h] = 0.f;
  {
    const ushort16* pb8 = PbT8 + (size_t)(b * 64 + (dhu << 5)) * PBT_STRIDE + j * 8;
    const float* sb = sbL + (dhu << 8);
    const float* wb = Wb2T + (dhu << 8) * NH;   // uniform base -> s_load
#pragma unroll 2
    for (int gg = 0; gg < 32; ++gg) {
      uint4 pk = *(const uint4*)(pb8 + (size_t)gg * PBT_STRIDE);  // 8 bf16
      float4 sv0 = *(const float4*)(sb + gg * 8);
      float4 sv1 = *(const float4*)(sb + gg * 8 + 4);
      float s0 = fast_silu(sv0.x - bf16_lo(pk.x));
      float s1 = fast_silu(sv0.y - bf16_hi(pk.x));
      float s2 = fast_silu(sv0.z - bf16_lo(pk.y));
      float s3 = fast_silu(sv0.w - bf16_hi(pk.y));
      float s4 = fast_silu(sv1.x - bf16_lo(pk.z));
      float s5 = fast_silu(sv1.y - bf16_hi(pk.z));
      float s6 = fast_silu(sv1.z - bf16_lo(pk.w));
      float s7 = fast_silu(sv1.w - bf16_hi(pk.w));
      const float* w0 = wb + gg * 8 * NH;
#pragma unroll
      for (int h = 0; h < NH; ++h) {
        float a = fmaf(s0, w0[h], s1 * w0[NH + h]);
        float c = fmaf(s2, w0[2 * NH + h], s3 * w0[3 * NH + h]);
        float e = fmaf(s4, w0[4 * NH + h], s5 * w0[5 * NH + h]);
        float f = fmaf(s6, w0[6 * NH + h], s7 * w0[7 * NH + h]);
        bp[h] += (a + c) + (e + f);
      }
    }
  }
  {
    float4* red2a = (float4*)uni;         // [dh][j] heads 0-3
    float4* red2b = red2a + 512;          // [dh][j] heads 4-7
    red2a[dh * NTOK + j] = make_float4(bp[0], bp[1], bp[2], bp[3]);
    red2b[dh * NTOK + j] = make_float4(bp[4], bp[5], bp[6], bp[7]);
  }
  __syncthreads();

  // ---- combine partials; scores for heads dh*4+c ----
  float score[4], ex[4];
  {
    const float4* red2a = (const float4*)uni;
    const float4* red2b = red2a + 512;
    const float4* sel = dh ? red2b : red2a;
    float4 ra = sel[j];
    float4 rb = sel[NTOK + j];
    score[0] = qk[0] * 0.125f + ra.x + rb.x;
    score[1] = qk[1] * 0.125f + ra.y + rb.y;
    score[2] = qk[2] * 0.125f + ra.z + rb.z;
    score[3] = qk[3] * 0.125f + ra.w + rb.w;   // bb2 softmax-invariant, dropped
  }

  // ---- softmax over j ----
#pragma unroll
  for (int c = 0; c < 4; ++c) {
    float m = score[c];
#pragma unroll
    for (int off = 32; off >= 1; off >>= 1) m = fmaxf(m, __shfl_xor(m, off));
    if (lane == 0) redm[dh][c][w4] = m;
  }
  __syncthreads();
#pragma unroll
  for (int c = 0; c < 4; ++c) {
    float m = fmaxf(fmaxf(redm[dh][c][0], redm[dh][c][1]),
                    fmaxf(redm[dh][c][2], redm[dh][c][3]));
    float e = __expf(score[c] - m);
    ex[c] = e;
    float s = e;
#pragma unroll
    for (int off = 32; off >= 1; off >>= 1) s += __shfl_xor(s, off);
    if (lane == 0) reds[dh][c][w4] = s;
  }
  __syncthreads();
  {
    float4 w;
    float s0 = reds[dh][0][0] + reds[dh][0][1] + reds[dh][0][2] + reds[dh][0][3];
    float s1 = reds[dh][1][0] + reds[dh][1][1] + reds[dh][1][2] + reds[dh][1][3];
    float s2 = reds[dh][2][0] + reds[dh][2][1] + reds[dh][2][2] + reds[dh][2][3];
    float s3 = reds[dh][3][0] + reds[dh][3][1] + reds[dh][3][2] + reds[dh][3][3];
    w.x = ex[0] * __builtin_amdgcn_rcpf(s0);
    w.y = ex[1] * __builtin_amdgcn_rcpf(s1);
    w.z = ex[2] * __builtin_amdgcn_rcpf(s2);
    w.w = ex[3] * __builtin_amdgcn_rcpf(s3);
    // stash for phase 2 (aliases red2: two barriers since last red2 read)
    float4* sWa = (float4*)uni;
    float4* sWb = sWa + 256;
    if (dh == 0) sWa[j] = w; else sWb[j] = w;
    // Wsm[b][i][h][j]: contiguous 8KB per block -> no L2 set aliasing on writes
    float* wout = Wsm + ((size_t)blk * NH + (dh << 2)) * NTOK + j;
    wout[0] = w.x;
    wout[NTOK] = w.y;
    wout[2 * NTOK] = w.z;
    wout[3 * NTOK] = w.w;
  }
  __syncthreads();

  // ---- phase 2: accumulate g[h][d] (lane = feature d) ----
  {
    int d = t;
    float sv = Sv[(size_t)blk * DM + d];
    float g[NH];
#pragma unroll
    for (int h = 0; h < NH; ++h) g[h] = 0.f;
    const float4* sWa = (const float4*)uni;
    const float4* sWb = sWa + 256;
    const ushort16* pq = PvQ + (size_t)(b * 64) * PVQ_STRIDE + d * 4;
#pragma unroll 2
    for (int jq = 0; jq < 64; ++jq) {
      uint2 pk = *(const uint2*)(pq + (size_t)jq * PVQ_STRIDE);  // 4 bf16 (4 j's)
      float s0 = fast_silu(sv - bf16_lo(pk.x));
      float s1 = fast_silu(sv - bf16_hi(pk.x));
      float s2 = fast_silu(sv - bf16_lo(pk.y));
      float s3 = fast_silu(sv - bf16_hi(pk.y));
      int j0 = jq * 4;
      float4 a0 = sWa[j0 + 0], b0 = sWb[j0 + 0];
      float4 a1 = sWa[j0 + 1], b1 = sWb[j0 + 1];
      float4 a2 = sWa[j0 + 2], b2 = sWb[j0 + 2];
      float4 a3 = sWa[j0 + 3], b3 = sWb[j0 + 3];
      g[0] = fmaf(s0, a0.x, g[0]); g[1] = fmaf(s0, a0.y, g[1]);
      g[2] = fmaf(s0, a0.z, g[2]); g[3] = fmaf(s0, a0.w, g[3]);
      g[4] = fmaf(s0, b0.x, g[4]); g[5] = fmaf(s0, b0.y, g[5]);
      g[6] = fmaf(s0, b0.z, g[6]); g[7] = fmaf(s0, b0.w, g[7]);
      g[0] = fmaf(s1, a1.x, g[0]); g[1] = fmaf(s1, a1.y, g[1]);
      g[2] = fmaf(s1, a1.z, g[2]); g[3] = fmaf(s1, a1.w, g[3]);
      g[4] = fmaf(s1, b1.x, g[4]); g[5] = fmaf(s1, b1.y, g[5]);
      g[6] = fmaf(s1, b1.z, g[6]); g[7] = fmaf(s1, b1.w, g[7]);
      g[0] = fmaf(s2, a2.x, g[0]); g[1] = fmaf(s2, a2.y, g[1]);
      g[2] = fmaf(s2, a2.z, g[2]); g[3] = fmaf(s2, a2.w, g[3]);
      g[4] = fmaf(s2, b2.x, g[4]); g[5] = fmaf(s2, b2.y, g[5]);
      g[6] = fmaf(s2, b2.z, g[6]); g[7] = fmaf(s2, b2.w, g[7]);
      g[0] = fmaf(s3, a3.x, g[0]); g[1] = fmaf(s3, a3.y, g[1]);
      g[2] = fmaf(s3, a3.z, g[2]); g[3] = fmaf(s3, a3.w, g[3]);
      g[4] = fmaf(s3, b3.x, g[4]); g[5] = fmaf(s3, b3.y, g[5]);
      g[6] = fmaf(s3, b3.z, g[6]); g[7] = fmaf(s3, b3.w, g[7]);
    }
#pragma unroll
    for (int h = 0; h < NH; ++h)
      Gbf[((size_t)blk * NH + h) * DM + d] = bf16_rne(g[h]);
  }
}

// ---------------- out GEMM: out = Wsm @ V + G @ Wv2^T + bv2, per head ----------------
// grid (8 i-tiles, 8 heads), 256 thr, 64x64 tile, 4x4 micro.
__global__ __launch_bounds__(256) void out_gemm(
    const ushort16* __restrict__ Gbf, const float* __restrict__ Wsm,
    const float* __restrict__ Wv2, const float* __restrict__ V,
    const float* __restrict__ bv2, float* __restrict__ out) {
  __shared__ float As[64][33];
  __shared__ float Bs[64][33];
  int t = threadIdx.x;
  int bm = blockIdx.x;       // 64-query tile
  int h = blockIdx.y;        // head
  int b = bm >> 2;
  int lrow = t >> 2, lk = (t & 3) * 8;
  int tx = t & 15, ty = t >> 4;
  float acc[4][4] = {};

  // ---- GEMM1: G(i x d) @ Wv2_h^T, K = 512 ----
  {
    const ushort16* Arow = Gbf + ((size_t)(bm * 64 + lrow) * NH + h) * DM + lk;
    const float* Brow = Wv2 + (size_t)(h * 64 + lrow) * DM + lk;
    for (int k0 = 0; k0 < DM; k0 += 32) {
      uint4 ga = *(const uint4*)(Arow + k0);
      float4 wa = *(const float4*)(Brow + k0);
      float4 wbv = *(const float4*)(Brow + k0 + 4);
      __syncthreads();
      As[lrow][lk + 0] = bf16_lo(ga.x); As[lrow][lk + 1] = bf16_hi(ga.x);
      As[lrow][lk + 2] = bf16_lo(ga.y); As[lrow][lk + 3] = bf16_hi(ga.y);
      As[lrow][lk + 4] = bf16_lo(ga.z); As[lrow][lk + 5] = bf16_hi(ga.z);
      As[lrow][lk + 6] = bf16_lo(ga.w); As[lrow][lk + 7] = bf16_hi(ga.w);
      Bs[lrow][lk + 0] = wa.x;  Bs[lrow][lk + 1] = wa.y;
      Bs[lrow][lk + 2] = wa.z;  Bs[lrow][lk + 3] = wa.w;
      Bs[lrow][lk + 4] = wbv.x; Bs[lrow][lk + 5] = wbv.y;
      Bs[lrow][lk + 6] = wbv.z; Bs[lrow][lk + 7] = wbv.w;
      __syncthreads();
#pragma unroll
      for (int kk = 0; kk < 32; ++kk) {
        float a0 = As[ty * 4 + 0][kk], a1 = As[ty * 4 + 1][kk];
        float a2 = As[ty * 4 + 2][kk], a3 = As[ty * 4 + 3][kk];
        float b0 = Bs[tx * 4 + 0][kk], b1 = Bs[tx * 4 + 1][kk];
        float b2 = Bs[tx * 4 + 2][kk], b3 = Bs[tx * 4 + 3][kk];
        acc[0][0] = fmaf(a0, b0, acc[0][0]); acc[0][1] = fmaf(a0, b1, acc[0][1]);
        acc[0][2] = fmaf(a0, b2, acc[0][2]); acc[0][3] = fmaf(a0, b3, acc[0][3]);
        acc[1][0] = fmaf(a1, b0, acc[1][0]); acc[1][1] = fmaf(a1, b1, acc[1][1]);
        acc[1][2] = fmaf(a1, b2, acc[1][2]); acc[1][3] = fmaf(a1, b3, acc[1][3]);
        acc[2][0] = fmaf(a2, b0, acc[2][0]); acc[2][1] = fmaf(a2, b1, acc[2][1]);
        acc[2][2] = fmaf(a2, b2, acc[2][2]); acc[2][3] = fmaf(a2, b3, acc[2][3]);
        acc[3][0] = fmaf(a3, b0, acc[3][0]); acc[3][1] = fmaf(a3, b1, acc[3][1]);
        acc[3][2] = fmaf(a3, b2, acc[3][2]); acc[3][3] = fmaf(a3, b3, acc[3][3]);
      }
    }
  }

  // ---- GEMM2: Wsm(i x j) @ V(j x dp), K = 256 ----
  {
    int row = bm * 64 + lrow;   // global query row
    const float* A2row = Wsm + ((size_t)row * NH + h) * NTOK + lk;
    int lrow2 = t >> 3, lc = (t & 7) * 8;
    const float* Vrow = V + ((size_t)(b * NH + h) * NTOK + lrow2) * HDIM + lc;
    float (*Vs)[65] = (float(*)[65])&Bs[0][0];   // 32x65 = 2080 <= 64x33
    for (int k0 = 0; k0 < NTOK; k0 += 32) {
      float4 a1 = *(const float4*)(A2row + k0);
      float4 a2 = *(const float4*)(A2row + k0 + 4);
      float4 v1 = *(const float4*)(Vrow + (size_t)k0 * HDIM);
      float4 v2 = *(const float4*)(Vrow + (size_t)k0 * HDIM + 4);
      __syncthreads();
      As[lrow][lk + 0] = a1.x; As[lrow][lk + 1] = a1.y;
      As[lrow][lk + 2] = a1.z; As[lrow][lk + 3] = a1.w;
      As[lrow][lk + 4] = a2.x; As[lrow][lk + 5] = a2.y;
      As[lrow][lk + 6] = a2.z; As[lrow][lk + 7] = a2.w;
      Vs[lrow2][lc + 0] = v1.x; Vs[lrow2][lc + 1] = v1.y;
      Vs[lrow2][lc + 2] = v1.z; Vs[lrow2][lc + 3] = v1.w;
      Vs[lrow2][lc + 4] = v2.x; Vs[lrow2][lc + 5] = v2.y;
      Vs[lrow2][lc + 6] = v2.z; Vs[lrow2][lc + 7] = v2.w;
      __syncthreads();
#pragma unroll
      for (int kk = 0; kk < 32; ++kk) {
        float a0 = As[ty * 4 + 0][kk], a1v = As[ty * 4 + 1][kk];
        float a2v = As[ty * 4 + 2][kk], a3v = As[ty * 4 + 3][kk];
        float4 bvv = *(const float4*)&Vs[kk][tx * 4];
        acc[0][0] = fmaf(a0, bvv.x, acc[0][0]); acc[0][1] = fmaf(a0, bvv.y, acc[0][1]);
        acc[0][2] = fmaf(a0, bvv.z, acc[0][2]); acc[0][3] = fmaf(a0, bvv.w, acc[0][3]);
        acc[1][0] = fmaf(a1v, bvv.x, acc[1][0]); acc[1][1] = fmaf(a1v, bvv.y, acc[1][1]);
        acc[1][2] = fmaf(a1v, bvv.z, acc[1][2]); acc[1][3] = fmaf(a1v, bvv.w, acc[1][3]);
        acc[2][0] = fmaf(a2v, bvv.x, acc[2][0]); acc[2][1] = fmaf(a2v, bvv.y, acc[2][1]);
        acc[2][2] = fmaf(a2v, bvv.z, acc[2][2]); acc[2][3] = fmaf(a2v, bvv.w, acc[2][3]);
        acc[3][0] = fmaf(a3v, bvv.x, acc[3][0]); acc[3][1] = fmaf(a3v, bvv.y, acc[3][1]);
        acc[3][2] = fmaf(a3v, bvv.z, acc[3][2]); acc[3][3] = fmaf(a3v, bvv.w, acc[3][3]);
      }
    }
  }

  // ---- epilogue ----
  int o0 = h * 64 + tx * 4;
  float4 bvq = *(const float4*)(bv2 + o0);
#pragma unroll
  for (int r = 0; r < 4; ++r) {
    int bi = bm * 64 + ty * 4 + r;
    float4 res;
    res.x = acc[r][0] + bvq.x;
    res.y = acc[r][1] + bvq.y;
    res.z = acc[r][2] + bvq.z;
    res.w = acc[r][3] + bvq.w;
    *(float4*)&out[(size_t)bi * DM + o0] = res;
  }
}

extern "C" void kernel_launch(void* const* d_in, const int* in_sizes, int n_in,
                              void* d_out, int out_size, void* d_ws, size_t ws_size,
                              hipStream_t stream) {
  const float* x      = (const float*)d_in[0];
  const float* coords = (const float*)d_in[1];
  const float* Wqkv   = (const float*)d_in[2];
  const float* bqkv   = (const float*)d_in[3];
  const float* Wb1    = (const float*)d_in[4];
  const float* bb1    = (const float*)d_in[5];
  const float* Wb2    = (const float*)d_in[6];
  // d_in[7] = bb2: softmax-invariant, unused
  const float* Wv1    = (const float*)d_in[8];
  const float* bv1    = (const float*)d_in[9];
  const float* Wv2    = (const float*)d_in[10];
  const float* bv2    = (const float*)d_in[11];
  float* outp = (float*)d_out;
  float* ws = (float*)d_ws;

  const size_t SZ = (size_t)BATCH * NTOK * DM;             // 262144 floats
  const size_t WSM_SZ = (size_t)BATCH * NH * NTOK * NTOK;  // 1048576 floats
  const size_t PBT_SZ = (size_t)BATCH * 64 * PBT_STRIDE;   // ushorts
  const size_t PVQ_SZ = (size_t)BATCH * 64 * PVQ_STRIDE;   // ushorts
  float* Qw    = ws;
  float* Kw    = ws + SZ;
  float* Sbw   = ws + 2 * SZ;
  float* Svw   = ws + 3 * SZ;
  float* Vw    = ws + 4 * SZ;
  float* Wb2T  = ws + 5 * SZ;                        // 4096 floats
  float* Wsm   = ws + 5 * SZ + 4096;                 // WSM_SZ floats
  ushort16* Gbf  = (ushort16*)(ws + 5 * SZ + 4096 + WSM_SZ);      // SZ*NH/DM... = 2M ushorts
  ushort16* PbT8 = (ushort16*)(ws + 5 * SZ + 4096 + 2 * WSM_SZ);  // PBT_SZ ushorts
  ushort16* PvQ  = PbT8 + PBT_SZ;

  hipLaunchKernelGGL(prep_pe, dim3((BATCH * NTOK * DM) / 256), dim3(256), 0, stream,
                     coords, Wb1, bb1, Wv1, bv1, Wb2,
                     Sbw, Svw, PbT8, PvQ, Wb2T);
  hipLaunchKernelGGL(qkv_gemm, dim3(8, 24), dim3(256), 0, stream,
                     x, Wqkv, bqkv, Qw, Kw, Vw);
  hipLaunchKernelGGL(attn_part, dim3(BATCH * NTOK), dim3(512), 0, stream,
                     Qw, Kw, Sbw, Svw, PbT8, PvQ, Wb2T, Wsm, Gbf);
  hipLaunchKernelGGL(out_gemm, dim3(8, 8), dim3(256), 0, stream,
                     Gbf, Wsm, Wv2, Vw, bv2, outp);
}

// Round 5
// 229.501 us; speedup vs baseline: 1.6333x; 1.6333x over previous
//
#include <hip/hip_runtime.h>

#define BATCH 2
#define NTOK 256
#define DM 512
#define NH 8
#define HDIM 64

// padded row strides (in ushorts) for the bf16 pair streams
#define PBT_STRIDE (NTOK * 8 + 64)   // 2112 ushorts
#define PVQ_STRIDE (DM * 4 + 64)     // 2112 ushorts

typedef unsigned int uint32;
typedef unsigned short ushort16;

static __device__ __forceinline__ float fast_silu(float x) {
  return x * __builtin_amdgcn_rcpf(1.0f + __expf(-x));
}
static __device__ __forceinline__ ushort16 bf16_rne(float x) {
  uint32 u = __float_as_uint(x);
  u += 0x7fffu + ((u >> 16) & 1u);
  return (ushort16)(u >> 16);
}
static __device__ __forceinline__ float bf16_lo(uint32 u) {
  return __uint_as_float(u << 16);
}
static __device__ __forceinline__ float bf16_hi(uint32 u) {
  return __uint_as_float(u & 0xffff0000u);
}

// ---------------- prep: per-token MLP1 projections (bf16 packed) + Wb2^T ----------------
__global__ __launch_bounds__(256) void prep_pe(
    const float* __restrict__ coords,
    const float* __restrict__ Wb1, const float* __restrict__ bb1,
    const float* __restrict__ Wv1, const float* __restrict__ bv1,
    const float* __restrict__ Wb2,
    float* __restrict__ Sb, float* __restrict__ Sv,
    ushort16* __restrict__ PbT8, ushort16* __restrict__ PvQ,
    float* __restrict__ Wb2T) {
  int idx = blockIdx.x * 256 + threadIdx.x;   // (b,i,d), d fastest
  int d = idx & (DM - 1);
  int i = (idx >> 9) & (NTOK - 1);
  int b = idx >> 17;
  const float* cp = coords + (b * NTOK + i) * 3;
  float c0 = cp[0], c1 = cp[1], c2 = cp[2];
  float pb = Wb1[d * 3 + 0] * c0 + Wb1[d * 3 + 1] * c1 + Wb1[d * 3 + 2] * c2;
  float pv = Wv1[d * 3 + 0] * c0 + Wv1[d * 3 + 1] * c1 + Wv1[d * 3 + 2] * c2;
  Sb[idx] = pb + bb1[d];
  Sv[idx] = pv + bv1[d];
  PbT8[(size_t)(b * 64 + (d >> 3)) * PBT_STRIDE + i * 8 + (d & 7)] = bf16_rne(pb);
  PvQ [(size_t)(b * 64 + (i >> 2)) * PVQ_STRIDE + d * 4 + (i & 3)] = bf16_rne(pv);
  if (idx < DM * NH) {
    int h = idx & 7, dd = idx >> 3;
    Wb2T[idx] = Wb2[h * DM + dd];
  }
}

// ---------------- QKV projection GEMM ----------------
__global__ __launch_bounds__(256) void qkv_gemm(
    const float* __restrict__ X, const float* __restrict__ W,
    const float* __restrict__ bqkv,
    float* __restrict__ Q, float* __restrict__ K, float* __restrict__ V) {
  __shared__ float Xs[64][33];
  __shared__ float Ws[64][33];
  int t = threadIdx.x;
  int bm = blockIdx.x, bn = blockIdx.y;
  int lrow = t >> 2, lk = (t & 3) * 8;
  const float* Xp = X + (bm * 64 + lrow) * DM + lk;
  const float* Wp = W + (bn * 64 + lrow) * DM + lk;
  int tx = t & 15, ty = t >> 4;
  float acc[4][4] = {};
  for (int k0 = 0; k0 < DM; k0 += 32) {
    float4 xa = *(const float4*)(Xp + k0);
    float4 xb = *(const float4*)(Xp + k0 + 4);
    float4 wa = *(const float4*)(Wp + k0);
    float4 wb = *(const float4*)(Wp + k0 + 4);
    __syncthreads();
    Xs[lrow][lk + 0] = xa.x; Xs[lrow][lk + 1] = xa.y;
    Xs[lrow][lk + 2] = xa.z; Xs[lrow][lk + 3] = xa.w;
    Xs[lrow][lk + 4] = xb.x; Xs[lrow][lk + 5] = xb.y;
    Xs[lrow][lk + 6] = xb.z; Xs[lrow][lk + 7] = xb.w;
    Ws[lrow][lk + 0] = wa.x; Ws[lrow][lk + 1] = wa.y;
    Ws[lrow][lk + 2] = wa.z; Ws[lrow][lk + 3] = wa.w;
    Ws[lrow][lk + 4] = wb.x; Ws[lrow][lk + 5] = wb.y;
    Ws[lrow][lk + 6] = wb.z; Ws[lrow][lk + 7] = wb.w;
    __syncthreads();
#pragma unroll
    for (int kk = 0; kk < 32; ++kk) {
      float a0 = Xs[ty * 4 + 0][kk], a1 = Xs[ty * 4 + 1][kk];
      float a2 = Xs[ty * 4 + 2][kk], a3 = Xs[ty * 4 + 3][kk];
      float b0 = Ws[tx * 4 + 0][kk], b1 = Ws[tx * 4 + 1][kk];
      float b2 = Ws[tx * 4 + 2][kk], b3 = Ws[tx * 4 + 3][kk];
      acc[0][0] = fmaf(a0, b0, acc[0][0]); acc[0][1] = fmaf(a0, b1, acc[0][1]);
      acc[0][2] = fmaf(a0, b2, acc[0][2]); acc[0][3] = fmaf(a0, b3, acc[0][3]);
      acc[1][0] = fmaf(a1, b0, acc[1][0]); acc[1][1] = fmaf(a1, b1, acc[1][1]);
      acc[1][2] = fmaf(a1, b2, acc[1][2]); acc[1][3] = fmaf(a1, b3, acc[1][3]);
      acc[2][0] = fmaf(a2, b0, acc[2][0]); acc[2][1] = fmaf(a2, b1, acc[2][1]);
      acc[2][2] = fmaf(a2, b2, acc[2][2]); acc[2][3] = fmaf(a2, b3, acc[2][3]);
      acc[3][0] = fmaf(a3, b0, acc[3][0]); acc[3][1] = fmaf(a3, b1, acc[3][1]);
      acc[3][2] = fmaf(a3, b2, acc[3][2]); acc[3][3] = fmaf(a3, b3, acc[3][3]);
    }
  }
#pragma unroll
  for (int r = 0; r < 4; ++r) {
    int row = bm * 64 + ty * 4 + r;
    int b = row >> 8, i = row & (NTOK - 1);
#pragma unroll
    for (int c = 0; c < 4; ++c) {
      int n = bn * 64 + tx * 4 + c;
      float val = acc[r][c] + bqkv[n];
      if (n < DM) {
        Q[(b * NTOK + i) * DM + n] = val;
      } else if (n < 2 * DM) {
        int u = n - DM; int h = u >> 6, dp = u & 63;
        K[((b * NH + h) * NTOK + i) * HDIM + dp] = val;
      } else {
        int u = n - 2 * DM; int h = u >> 6, dp = u & 63;
        V[((b * NH + h) * NTOK + i) * HDIM + dp] = val;
      }
    }
  }
}

// ---------------- attn_score: QK + bias MLP + softmax ----------------
// One block per query, 1024 threads = 16 waves: (j = t&255, dq = t>>8).
// Each dq group owns d in [dq*128, dq*128+128) of the bias reduction and 2 heads.
// Q/Sb/Wb2T reads are wave-uniform -> scalar loads. Only K and PbT8 are vector streams.
__global__ __launch_bounds__(1024, 8) void attn_score(
    const float* __restrict__ Q, const float* __restrict__ K,
    const float* __restrict__ Sb,
    const ushort16* __restrict__ PbT8, const float* __restrict__ Wb2T,
    float* __restrict__ Wsm, float* __restrict__ WsmT) {
  __shared__ float red[4][NTOK][NH];   // 32 KB bias partials
  __shared__ float redm[4][2][4];
  __shared__ float reds[4][2][4];

  int t = threadIdx.x;
  // bijective XCD swizzle: XCD k gets 64 contiguous queries of one batch
  int blk = ((blockIdx.x & 7) << 6) + (blockIdx.x >> 3);   // b*NTOK + i
  int b = blk >> 8;
  int j = t & (NTOK - 1);
  int dq = t >> 8;
  int dqu = __builtin_amdgcn_readfirstlane(dq);
  int lane = t & 63;
  int w4 = (t >> 6) & 3;

  // ---- QK^T for this group's 2 heads (q via scalar loads) ----
  float qk[2];
  {
    const float* kb = K + ((size_t)(b * NH + (dqu << 1)) * NTOK + j) * HDIM;
    const float* qb = Q + (size_t)blk * DM + (dqu << 7);
#pragma unroll
    for (int c = 0; c < 2; ++c) {
      const float* kr = kb + (size_t)c * NTOK * HDIM;
      const float* qr = qb + c * HDIM;   // uniform -> s_load
      float acc = 0.f;
#pragma unroll
      for (int dg = 0; dg < HDIM / 4; ++dg) {
        float4 kv = *(const float4*)(kr + dg * 4);
        acc = fmaf(kv.x, qr[dg * 4 + 0], acc);
        acc = fmaf(kv.y, qr[dg * 4 + 1], acc);
        acc = fmaf(kv.z, qr[dg * 4 + 2], acc);
        acc = fmaf(kv.w, qr[dg * 4 + 3], acc);
      }
      qk[c] = acc;
    }
  }

  // ---- bias MLP partial over this group's 128 d ----
  float bp[NH];
#pragma unroll
  for (int h = 0; h < NH; ++h) bp[h] = 0.f;
  {
    const ushort16* pb8 = PbT8 + (size_t)(b * 64 + (dqu << 4)) * PBT_STRIDE + j * 8;
    const float* sb = Sb + (size_t)blk * DM + (dqu << 7);   // uniform -> s_load
    const float* wb = Wb2T + (dqu << 7) * NH;               // uniform -> s_load
#pragma unroll 2
    for (int gg = 0; gg < 16; ++gg) {
      uint4 pk = *(const uint4*)(pb8 + (size_t)gg * PBT_STRIDE);  // 8 bf16
      float s0 = fast_silu(sb[gg * 8 + 0] - bf16_lo(pk.x));
      float s1 = fast_silu(sb[gg * 8 + 1] - bf16_hi(pk.x));
      float s2 = fast_silu(sb[gg * 8 + 2] - bf16_lo(pk.y));
      float s3 = fast_silu(sb[gg * 8 + 3] - bf16_hi(pk.y));
      float s4 = fast_silu(sb[gg * 8 + 4] - bf16_lo(pk.z));
      float s5 = fast_silu(sb[gg * 8 + 5] - bf16_hi(pk.z));
      float s6 = fast_silu(sb[gg * 8 + 6] - bf16_lo(pk.w));
      float s7 = fast_silu(sb[gg * 8 + 7] - bf16_hi(pk.w));
      const float* w0 = wb + gg * 8 * NH;
#pragma unroll
      for (int h = 0; h < NH; ++h) {
        float a = fmaf(s0, w0[h], s1 * w0[NH + h]);
        float c = fmaf(s2, w0[2 * NH + h], s3 * w0[3 * NH + h]);
        float e = fmaf(s4, w0[4 * NH + h], s5 * w0[5 * NH + h]);
        float f = fmaf(s6, w0[6 * NH + h], s7 * w0[7 * NH + h]);
        bp[h] += (a + c) + (e + f);
      }
    }
  }
  red[dq][j][0] = bp[0]; red[dq][j][1] = bp[1];
  red[dq][j][2] = bp[2]; red[dq][j][3] = bp[3];
  red[dq][j][4] = bp[4]; red[dq][j][5] = bp[5];
  red[dq][j][6] = bp[6]; red[dq][j][7] = bp[7];
  __syncthreads();

  // ---- combine partials: this group's heads h = 2*dq + c ----
  float score[2], ex[2];
#pragma unroll
  for (int c = 0; c < 2; ++c) {
    int h = (dqu << 1) + c;
    float bias = (red[0][j][h] + red[1][j][h]) + (red[2][j][h] + red[3][j][h]);
    score[c] = qk[c] * 0.125f + bias;   // bb2 softmax-invariant, dropped
  }

  // ---- softmax over j (4 waves per dq group) ----
#pragma unroll
  for (int c = 0; c < 2; ++c) {
    float m = score[c];
#pragma unroll
    for (int off = 32; off >= 1; off >>= 1) m = fmaxf(m, __shfl_xor(m, off));
    if (lane == 0) redm[dq][c][w4] = m;
  }
  __syncthreads();
#pragma unroll
  for (int c = 0; c < 2; ++c) {
    float m = fmaxf(fmaxf(redm[dq][c][0], redm[dq][c][1]),
                    fmaxf(redm[dq][c][2], redm[dq][c][3]));
    float e = __expf(score[c] - m);
    ex[c] = e;
    float s = e;
#pragma unroll
    for (int off = 32; off >= 1; off >>= 1) s += __shfl_xor(s, off);
    if (lane == 0) reds[dq][c][w4] = s;
  }
  __syncthreads();
  {
    float s0 = reds[dq][0][0] + reds[dq][0][1] + reds[dq][0][2] + reds[dq][0][3];
    float s1 = reds[dq][1][0] + reds[dq][1][1] + reds[dq][1][2] + reds[dq][1][3];
    float w0 = ex[0] * __builtin_amdgcn_rcpf(s0);
    float w1 = ex[1] * __builtin_amdgcn_rcpf(s1);
    // WsmT[q][j][h]: 8 contiguous floats per j (scalar-load friendly)
    float2* wt = (float2*)(WsmT + (size_t)blk * (NH * NTOK) + j * NH + (dqu << 1));
    *wt = make_float2(w0, w1);
    // Wsm[q][h][j]: rows over j for out_gemm
    float* wo = Wsm + ((size_t)blk * NH + (dqu << 1)) * NTOK + j;
    wo[0] = w0;
    wo[NTOK] = w1;
  }
}

// ---------------- g_accum: g[q][h][d] = sum_j w[q][h][j] * silu(Sv[q,d]-Pv[j,d]) ----
// One block per (query, d-half). 256 threads, no LDS. Weights via uniform s_loads.
__global__ __launch_bounds__(256) void g_accum(
    const float* __restrict__ Sv, const ushort16* __restrict__ PvQ,
    const float* __restrict__ WsmT, ushort16* __restrict__ Gbf) {
  int t = threadIdx.x;
  // bijective XCD swizzle over 1024 blocks: XCD k gets 64 contiguous queries
  int lin = ((blockIdx.x & 7) << 7) + (blockIdx.x >> 3);
  int q = lin >> 1;
  int half = lin & 1;
  int b = q >> 8;
  int d = (half << 8) + t;
  float sv = Sv[(size_t)q * DM + d];
  const float* wt = WsmT + (size_t)q * (NH * NTOK);   // uniform -> s_load
  const ushort16* pq = PvQ + (size_t)(b * 64) * PVQ_STRIDE + d * 4;
  float g[NH];
#pragma unroll
  for (int h = 0; h < NH; ++h) g[h] = 0.f;
#pragma unroll 2
  for (int jq = 0; jq < 64; ++jq) {
    uint2 pk = *(const uint2*)(pq + (size_t)jq * PVQ_STRIDE);  // 4 bf16 (4 j's)
    float s0 = fast_silu(sv - bf16_lo(pk.x));
    float s1 = fast_silu(sv - bf16_hi(pk.x));
    float s2 = fast_silu(sv - bf16_lo(pk.y));
    float s3 = fast_silu(sv - bf16_hi(pk.y));
    const float* w0 = wt + (jq * 4) * NH;
#pragma unroll
    for (int h = 0; h < NH; ++h) g[h] = fmaf(s0, w0[h], g[h]);
#pragma unroll
    for (int h = 0; h < NH; ++h) g[h] = fmaf(s1, w0[NH + h], g[h]);
#pragma unroll
    for (int h = 0; h < NH; ++h) g[h] = fmaf(s2, w0[2 * NH + h], g[h]);
#pragma unroll
    for (int h = 0; h < NH; ++h) g[h] = fmaf(s3, w0[3 * NH + h], g[h]);
  }
#pragma unroll
  for (int h = 0; h < NH; ++h)
    Gbf[((size_t)q * NH + h) * DM + d] = bf16_rne(g[h]);
}

// ---------------- out GEMM: out = Wsm @ V + G @ Wv2^T + bv2, per head ----------------
// grid (16 i-tiles of 32, 8 heads), 256 thr, 32x64 tile, 2x4 micro.
__global__ __launch_bounds__(256) void out_gemm(
    const ushort16* __restrict__ Gbf, const float* __restrict__ Wsm,
    const float* __restrict__ Wv2, const float* __restrict__ V,
    const float* __restrict__ bv2, float* __restrict__ out) {
  __shared__ float As[32][33];
  __shared__ float Bs[64][33];
  int t = threadIdx.x;
  int bm = blockIdx.x;       // 32-query tile
  int h = blockIdx.y;        // head
  int tx = t & 15, ty = t >> 4;
  float acc[2][4] = {};

  // ---- GEMM1: G(32 x 512, bf16) @ Wv2_h^T(512 x 64), K-tile 32 ----
  {
    int lrA = t >> 3, lkA = (t & 7) * 4;
    int lrB = t >> 2, lkB = (t & 3) * 8;
    const ushort16* Ap = Gbf + ((size_t)(bm * 32 + lrA) * NH + h) * DM + lkA;
    const float* Bp = Wv2 + (size_t)(h * 64 + lrB) * DM + lkB;
    for (int k0 = 0; k0 < DM; k0 += 32) {
      uint2 ga = *(const uint2*)(Ap + k0);
      float4 w1 = *(const float4*)(Bp + k0);
      float4 w2 = *(const float4*)(Bp + k0 + 4);
      __syncthreads();
      As[lrA][lkA + 0] = bf16_lo(ga.x); As[lrA][lkA + 1] = bf16_hi(ga.x);
      As[lrA][lkA + 2] = bf16_lo(ga.y); As[lrA][lkA + 3] = bf16_hi(ga.y);
      Bs[lrB][lkB + 0] = w1.x; Bs[lrB][lkB + 1] = w1.y;
      Bs[lrB][lkB + 2] = w1.z; Bs[lrB][lkB + 3] = w1.w;
      Bs[lrB][lkB + 4] = w2.x; Bs[lrB][lkB + 5] = w2.y;
      Bs[lrB][lkB + 6] = w2.z; Bs[lrB][lkB + 7] = w2.w;
      __syncthreads();
#pragma unroll
      for (int kk = 0; kk < 32; ++kk) {
        float a0 = As[ty * 2 + 0][kk], a1 = As[ty * 2 + 1][kk];
        float b0 = Bs[tx * 4 + 0][kk], b1 = Bs[tx * 4 + 1][kk];
        float b2 = Bs[tx * 4 + 2][kk], b3 = Bs[tx * 4 + 3][kk];
        acc[0][0] = fmaf(a0, b0, acc[0][0]); acc[0][1] = fmaf(a0, b1, acc[0][1]);
        acc[0][2] = fmaf(a0, b2, acc[0][2]); acc[0][3] = fmaf(a0, b3, acc[0][3]);
        acc[1][0] = fmaf(a1, b0, acc[1][0]); acc[1][1] = fmaf(a1, b1, acc[1][1]);
        acc[1][2] = fmaf(a1, b2, acc[1][2]); acc[1][3] = fmaf(a1, b3, acc[1][3]);
      }
    }
  }

  // ---- GEMM2: Wsm(32 x 256) @ V(256 x 64), K-tile 32 ----
  {
    int lrA = t >> 3, lkA = (t & 7) * 4;
    int lrV = t >> 3, lcV = (t & 7) * 8;
    int b = bm >> 3;
    const float* A2p = Wsm + ((size_t)(bm * 32 + lrA) * NH + h) * NTOK + lkA;
    const float* Vp = V + ((size_t)(b * NH + h) * NTOK + lrV) * HDIM + lcV;
    float (*Vs)[65] = (float(*)[65])&Bs[0][0];   // 32x65 = 2080 <= 64x33
    for (int k0 = 0; k0 < NTOK; k0 += 32) {
      float4 a4 = *(const float4*)(A2p + k0);
      float4 v1 = *(const float4*)(Vp + (size_t)k0 * HDIM);
      float4 v2 = *(const float4*)(Vp + (size_t)k0 * HDIM + 4);
      __syncthreads();
      As[lrA][lkA + 0] = a4.x; As[lrA][lkA + 1] = a4.y;
      As[lrA][lkA + 2] = a4.z; As[lrA][lkA + 3] = a4.w;
      Vs[lrV][lcV + 0] = v1.x; Vs[lrV][lcV + 1] = v1.y;
      Vs[lrV][lcV + 2] = v1.z; Vs[lrV][lcV + 3] = v1.w;
      Vs[lrV][lcV + 4] = v2.x; Vs[lrV][lcV + 5] = v2.y;
      Vs[lrV][lcV + 6] = v2.z; Vs[lrV][lcV + 7] = v2.w;
      __syncthreads();
#pragma unroll
      for (int kk = 0; kk < 32; ++kk) {
        float a0 = As[ty * 2 + 0][kk], a1 = As[ty * 2 + 1][kk];
        float b0 = Vs[kk][tx * 4 + 0], b1 = Vs[kk][tx * 4 + 1];
        float b2 = Vs[kk][tx * 4 + 2], b3 = Vs[kk][tx * 4 + 3];
        acc[0][0] = fmaf(a0, b0, acc[0][0]); acc[0][1] = fmaf(a0, b1, acc[0][1]);
        acc[0][2] = fmaf(a0, b2, acc[0][2]); acc[0][3] = fmaf(a0, b3, acc[0][3]);
        acc[1][0] = fmaf(a1, b0, acc[1][0]); acc[1][1] = fmaf(a1, b1, acc[1][1]);
        acc[1][2] = fmaf(a1, b2, acc[1][2]); acc[1][3] = fmaf(a1, b3, acc[1][3]);
      }
    }
  }

  // ---- epilogue ----
  int o0 = h * 64 + tx * 4;
  float4 bvq = *(const float4*)(bv2 + o0);
#pragma unroll
  for (int r = 0; r < 2; ++r) {
    int bi = bm * 32 + ty * 2 + r;
    float4 res;
    res.x = acc[r][0] + bvq.x;
    res.y = acc[r][1] + bvq.y;
    res.z = acc[r][2] + bvq.z;
    res.w = acc[r][3] + bvq.w;
    *(float4*)&out[(size_t)bi * DM + o0] = res;
  }
}

extern "C" void kernel_launch(void* const* d_in, const int* in_sizes, int n_in,
                              void* d_out, int out_size, void* d_ws, size_t ws_size,
                              hipStream_t stream) {
  const float* x      = (const float*)d_in[0];
  const float* coords = (const float*)d_in[1];
  const float* Wqkv   = (const float*)d_in[2];
  const float* bqkv   = (const float*)d_in[3];
  const float* Wb1    = (const float*)d_in[4];
  const float* bb1    = (const float*)d_in[5];
  const float* Wb2    = (const float*)d_in[6];
  // d_in[7] = bb2: softmax-invariant, unused
  const float* Wv1    = (const float*)d_in[8];
  const float* bv1    = (const float*)d_in[9];
  const float* Wv2    = (const float*)d_in[10];
  const float* bv2    = (const float*)d_in[11];
  float* outp = (float*)d_out;
  float* ws = (float*)d_ws;

  const size_t SZ = (size_t)BATCH * NTOK * DM;             // 262144 floats
  const size_t WSM_SZ = (size_t)BATCH * NTOK * NH * NTOK;  // 1048576 floats
  const size_t PBT_SZ = (size_t)BATCH * 64 * PBT_STRIDE;   // ushorts
  float* Qw    = ws;
  float* Kw    = ws + SZ;
  float* Sbw   = ws + 2 * SZ;
  float* Svw   = ws + 3 * SZ;
  float* Vw    = ws + 4 * SZ;
  float* Wb2T  = ws + 5 * SZ;                        // 4096 floats
  float* Wsm   = ws + 5 * SZ + 4096;                 // [q][h][j]
  float* WsmT  = Wsm + WSM_SZ;                       // [q][j][h]
  ushort16* Gbf  = (ushort16*)(WsmT + WSM_SZ);       // [q][h][d] bf16
  ushort16* PbT8 = (ushort16*)(WsmT + 2 * WSM_SZ);   // after Gbf (WSM_SZ floats)
  ushort16* PvQ  = PbT8 + PBT_SZ;

  hipLaunchKernelGGL(prep_pe, dim3((BATCH * NTOK * DM) / 256), dim3(256), 0, stream,
                     coords, Wb1, bb1, Wv1, bv1, Wb2,
                     Sbw, Svw, PbT8, PvQ, Wb2T);
  hipLaunchKernelGGL(qkv_gemm, dim3(8, 24), dim3(256), 0, stream,
                     x, Wqkv, bqkv, Qw, Kw, Vw);
  hipLaunchKernelGGL(attn_score, dim3(BATCH * NTOK), dim3(1024), 0, stream,
                     Qw, Kw, Sbw, PbT8, Wb2T, Wsm, WsmT);
  hipLaunchKernelGGL(g_accum, dim3(BATCH * NTOK * 2), dim3(256), 0, stream,
                     Svw, PvQ, WsmT, Gbf);
  hipLaunchKernelGGL(out_gemm, dim3(16, 8), dim3(256), 0, stream,
                     Gbf, Wsm, Wv2, Vw, bv2, outp);
}

// Round 6
// 153.986 us; speedup vs baseline: 2.4343x; 1.4904x over previous
//
#include <hip/hip_runtime.h>

#define BATCH 2
#define NTOK 256
#define DM 512
#define NH 8
#define HDIM 64

// padded row strides (in ushorts) for the bf16 pair streams
#define PBT_STRIDE (NTOK * 8 + 64)   // 2112 ushorts
#define PVQ_STRIDE (DM * 4 + 64)     // 2112 ushorts

typedef unsigned int uint32;
typedef unsigned short ushort16;

static __device__ __forceinline__ float fast_silu(float x) {
  return x * __builtin_amdgcn_rcpf(1.0f + __expf(-x));
}
static __device__ __forceinline__ ushort16 bf16_rne(float x) {
  uint32 u = __float_as_uint(x);
  u += 0x7fffu + ((u >> 16) & 1u);
  return (ushort16)(u >> 16);
}
static __device__ __forceinline__ float bf16_lo(uint32 u) {
  return __uint_as_float(u << 16);
}
static __device__ __forceinline__ float bf16_hi(uint32 u) {
  return __uint_as_float(u & 0xffff0000u);
}

// ---------------- prep: per-token MLP1 projections (bf16 packed) + Wb2^T ----------------
__global__ __launch_bounds__(256) void prep_pe(
    const float* __restrict__ coords,
    const float* __restrict__ Wb1, const float* __restrict__ bb1,
    const float* __restrict__ Wv1, const float* __restrict__ bv1,
    const float* __restrict__ Wb2,
    float* __restrict__ Sb, float* __restrict__ Sv,
    ushort16* __restrict__ PbT8, ushort16* __restrict__ PvQ,
    float* __restrict__ Wb2T) {
  int idx = blockIdx.x * 256 + threadIdx.x;   // (b,i,d), d fastest
  int d = idx & (DM - 1);
  int i = (idx >> 9) & (NTOK - 1);
  int b = idx >> 17;
  const float* cp = coords + (b * NTOK + i) * 3;
  float c0 = cp[0], c1 = cp[1], c2 = cp[2];
  float pb = Wb1[d * 3 + 0] * c0 + Wb1[d * 3 + 1] * c1 + Wb1[d * 3 + 2] * c2;
  float pv = Wv1[d * 3 + 0] * c0 + Wv1[d * 3 + 1] * c1 + Wv1[d * 3 + 2] * c2;
  Sb[idx] = pb + bb1[d];
  Sv[idx] = pv + bv1[d];
  PbT8[(size_t)(b * 64 + (d >> 3)) * PBT_STRIDE + i * 8 + (d & 7)] = bf16_rne(pb);
  PvQ [(size_t)(b * 64 + (i >> 2)) * PVQ_STRIDE + d * 4 + (i & 3)] = bf16_rne(pv);
  if (idx < DM * NH) {
    int h = idx & 7, dd = idx >> 3;
    Wb2T[idx] = Wb2[h * DM + dd];
  }
}

// ---------------- QKV projection GEMM ----------------
__global__ __launch_bounds__(256) void qkv_gemm(
    const float* __restrict__ X, const float* __restrict__ W,
    const float* __restrict__ bqkv,
    float* __restrict__ Q, float* __restrict__ K, float* __restrict__ V) {
  __shared__ float Xs[64][33];
  __shared__ float Ws[64][33];
  int t = threadIdx.x;
  int bm = blockIdx.x, bn = blockIdx.y;
  int lrow = t >> 2, lk = (t & 3) * 8;
  const float* Xp = X + (bm * 64 + lrow) * DM + lk;
  const float* Wp = W + (bn * 64 + lrow) * DM + lk;
  int tx = t & 15, ty = t >> 4;
  float acc[4][4] = {};
  for (int k0 = 0; k0 < DM; k0 += 32) {
    float4 xa = *(const float4*)(Xp + k0);
    float4 xb = *(const float4*)(Xp + k0 + 4);
    float4 wa = *(const float4*)(Wp + k0);
    float4 wb = *(const float4*)(Wp + k0 + 4);
    __syncthreads();
    Xs[lrow][lk + 0] = xa.x; Xs[lrow][lk + 1] = xa.y;
    Xs[lrow][lk + 2] = xa.z; Xs[lrow][lk + 3] = xa.w;
    Xs[lrow][lk + 4] = xb.x; Xs[lrow][lk + 5] = xb.y;
    Xs[lrow][lk + 6] = xb.z; Xs[lrow][lk + 7] = xb.w;
    Ws[lrow][lk + 0] = wa.x; Ws[lrow][lk + 1] = wa.y;
    Ws[lrow][lk + 2] = wa.z; Ws[lrow][lk + 3] = wa.w;
    Ws[lrow][lk + 4] = wb.x; Ws[lrow][lk + 5] = wb.y;
    Ws[lrow][lk + 6] = wb.z; Ws[lrow][lk + 7] = wb.w;
    __syncthreads();
#pragma unroll
    for (int kk = 0; kk < 32; ++kk) {
      float a0 = Xs[ty * 4 + 0][kk], a1 = Xs[ty * 4 + 1][kk];
      float a2 = Xs[ty * 4 + 2][kk], a3 = Xs[ty * 4 + 3][kk];
      float b0 = Ws[tx * 4 + 0][kk], b1 = Ws[tx * 4 + 1][kk];
      float b2 = Ws[tx * 4 + 2][kk], b3 = Ws[tx * 4 + 3][kk];
      acc[0][0] = fmaf(a0, b0, acc[0][0]); acc[0][1] = fmaf(a0, b1, acc[0][1]);
      acc[0][2] = fmaf(a0, b2, acc[0][2]); acc[0][3] = fmaf(a0, b3, acc[0][3]);
      acc[1][0] = fmaf(a1, b0, acc[1][0]); acc[1][1] = fmaf(a1, b1, acc[1][1]);
      acc[1][2] = fmaf(a1, b2, acc[1][2]); acc[1][3] = fmaf(a1, b3, acc[1][3]);
      acc[2][0] = fmaf(a2, b0, acc[2][0]); acc[2][1] = fmaf(a2, b1, acc[2][1]);
      acc[2][2] = fmaf(a2, b2, acc[2][2]); acc[2][3] = fmaf(a2, b3, acc[2][3]);
      acc[3][0] = fmaf(a3, b0, acc[3][0]); acc[3][1] = fmaf(a3, b1, acc[3][1]);
      acc[3][2] = fmaf(a3, b2, acc[3][2]); acc[3][3] = fmaf(a3, b3, acc[3][3]);
    }
  }
#pragma unroll
  for (int r = 0; r < 4; ++r) {
    int row = bm * 64 + ty * 4 + r;
    int b = row >> 8, i = row & (NTOK - 1);
#pragma unroll
    for (int c = 0; c < 4; ++c) {
      int n = bn * 64 + tx * 4 + c;
      float val = acc[r][c] + bqkv[n];
      if (n < DM) {
        Q[(b * NTOK + i) * DM + n] = val;
      } else if (n < 2 * DM) {
        int u = n - DM; int h = u >> 6, dp = u & 63;
        K[((b * NH + h) * NTOK + i) * HDIM + dp] = val;
      } else {
        int u = n - 2 * DM; int h = u >> 6, dp = u & 63;
        V[((b * NH + h) * NTOK + i) * HDIM + dp] = val;
      }
    }
  }
}

// ---------------- qk_gemm: S[b][h][i][j] = 0.125 * Q_h(i,:)·K_h(j,:) ----------------
// grid (16 ij-tiles, 16 bh), 256 thr, 64x64 tile, K=64, coalesced K reads.
__global__ __launch_bounds__(256) void qk_gemm(
    const float* __restrict__ Q, const float* __restrict__ K,
    float* __restrict__ S) {
  __shared__ float Qs[64][33];
  __shared__ float Ks[64][33];
  int t = threadIdx.x;
  int bh = blockIdx.y;
  int b = bh >> 3, h = bh & 7;
  int i0 = (blockIdx.x >> 2) * 64;
  int j0 = (blockIdx.x & 3) * 64;
  int lrow = t >> 2, lk = (t & 3) * 8;
  const float* Qp = Q + (size_t)(b * NTOK + i0 + lrow) * DM + h * HDIM + lk;
  const float* Kp = K + ((size_t)(b * NH + h) * NTOK + j0 + lrow) * HDIM + lk;
  int tx = t & 15, ty = t >> 4;
  float acc[4][4] = {};
  for (int k0 = 0; k0 < HDIM; k0 += 32) {
    float4 qa = *(const float4*)(Qp + k0);
    float4 qb = *(const float4*)(Qp + k0 + 4);
    float4 ka = *(const float4*)(Kp + k0);
    float4 kb = *(const float4*)(Kp + k0 + 4);
    __syncthreads();
    Qs[lrow][lk + 0] = qa.x; Qs[lrow][lk + 1] = qa.y;
    Qs[lrow][lk + 2] = qa.z; Qs[lrow][lk + 3] = qa.w;
    Qs[lrow][lk + 4] = qb.x; Qs[lrow][lk + 5] = qb.y;
    Qs[lrow][lk + 6] = qb.z; Qs[lrow][lk + 7] = qb.w;
    Ks[lrow][lk + 0] = ka.x; Ks[lrow][lk + 1] = ka.y;
    Ks[lrow][lk + 2] = ka.z; Ks[lrow][lk + 3] = ka.w;
    Ks[lrow][lk + 4] = kb.x; Ks[lrow][lk + 5] = kb.y;
    Ks[lrow][lk + 6] = kb.z; Ks[lrow][lk + 7] = kb.w;
    __syncthreads();
#pragma unroll
    for (int kk = 0; kk < 32; ++kk) {
      float a0 = Qs[ty * 4 + 0][kk], a1 = Qs[ty * 4 + 1][kk];
      float a2 = Qs[ty * 4 + 2][kk], a3 = Qs[ty * 4 + 3][kk];
      float b0 = Ks[tx * 4 + 0][kk], b1 = Ks[tx * 4 + 1][kk];
      float b2 = Ks[tx * 4 + 2][kk], b3 = Ks[tx * 4 + 3][kk];
      acc[0][0] = fmaf(a0, b0, acc[0][0]); acc[0][1] = fmaf(a0, b1, acc[0][1]);
      acc[0][2] = fmaf(a0, b2, acc[0][2]); acc[0][3] = fmaf(a0, b3, acc[0][3]);
      acc[1][0] = fmaf(a1, b0, acc[1][0]); acc[1][1] = fmaf(a1, b1, acc[1][1]);
      acc[1][2] = fmaf(a1, b2, acc[1][2]); acc[1][3] = fmaf(a1, b3, acc[1][3]);
      acc[2][0] = fmaf(a2, b0, acc[2][0]); acc[2][1] = fmaf(a2, b1, acc[2][1]);
      acc[2][2] = fmaf(a2, b2, acc[2][2]); acc[2][3] = fmaf(a2, b3, acc[2][3]);
      acc[3][0] = fmaf(a3, b0, acc[3][0]); acc[3][1] = fmaf(a3, b1, acc[3][1]);
      acc[3][2] = fmaf(a3, b2, acc[3][2]); acc[3][3] = fmaf(a3, b3, acc[3][3]);
    }
  }
#pragma unroll
  for (int r = 0; r < 4; ++r) {
    float4 res;
    res.x = acc[r][0] * 0.125f;
    res.y = acc[r][1] * 0.125f;
    res.z = acc[r][2] * 0.125f;
    res.w = acc[r][3] * 0.125f;
    *(float4*)&S[((size_t)bh * NTOK + i0 + ty * 4 + r) * NTOK + j0 + tx * 4] = res;
  }
}

// ---------------- attn_score: bias MLP + score + softmax ----------------
// One block per query, 1024 threads = 16 waves: (j = t&255, dq = t>>8).
// Each dq group owns d in [dq*128, dq*128+128) of the bias reduction and 2 heads.
// QK^T comes precomputed (coalesced read). Sb/Wb2T are wave-uniform scalar loads.
__global__ __launch_bounds__(1024) void attn_score(
    const float* __restrict__ Sqk, const float* __restrict__ Sb,
    const ushort16* __restrict__ PbT8, const float* __restrict__ Wb2T,
    float* __restrict__ Wsm, float* __restrict__ WsmT) {
  __shared__ float red[4][NTOK][9];    // 36 KB, pad 9 -> conflict-free; reused for wT
  __shared__ float redm[4][2][4];
  __shared__ float reds[4][2][4];

  int t = threadIdx.x;
  // bijective XCD swizzle: XCD k gets 64 contiguous queries of one batch
  int blk = ((blockIdx.x & 7) << 6) + (blockIdx.x >> 3);   // b*NTOK + i
  int b = blk >> 8;
  int qi = blk & (NTOK - 1);
  int j = t & (NTOK - 1);
  int dq = t >> 8;
  int dqu = __builtin_amdgcn_readfirstlane(dq);
  int lane = t & 63;
  int w4 = (t >> 6) & 3;

  // ---- bias MLP partial over this group's 128 d ----
  float bp[NH];
#pragma unroll
  for (int h = 0; h < NH; ++h) bp[h] = 0.f;
  {
    const ushort16* pb8 = PbT8 + (size_t)(b * 64 + (dqu << 4)) * PBT_STRIDE + j * 8;
    const float* sb = Sb + (size_t)blk * DM + (dqu << 7);   // uniform -> s_load
    const float* wb = Wb2T + (dqu << 7) * NH;               // uniform -> s_load
#pragma unroll 2
    for (int gg = 0; gg < 16; ++gg) {
      uint4 pk = *(const uint4*)(pb8 + (size_t)gg * PBT_STRIDE);  // 8 bf16
      float s0 = fast_silu(sb[gg * 8 + 0] - bf16_lo(pk.x));
      float s1 = fast_silu(sb[gg * 8 + 1] - bf16_hi(pk.x));
      float s2 = fast_silu(sb[gg * 8 + 2] - bf16_lo(pk.y));
      float s3 = fast_silu(sb[gg * 8 + 3] - bf16_hi(pk.y));
      float s4 = fast_silu(sb[gg * 8 + 4] - bf16_lo(pk.z));
      float s5 = fast_silu(sb[gg * 8 + 5] - bf16_hi(pk.z));
      float s6 = fast_silu(sb[gg * 8 + 6] - bf16_lo(pk.w));
      float s7 = fast_silu(sb[gg * 8 + 7] - bf16_hi(pk.w));
      const float* w0 = wb + gg * 8 * NH;
#pragma unroll
      for (int h = 0; h < NH; ++h) {
        float a = fmaf(s0, w0[h], s1 * w0[NH + h]);
        float c = fmaf(s2, w0[2 * NH + h], s3 * w0[3 * NH + h]);
        float e = fmaf(s4, w0[4 * NH + h], s5 * w0[5 * NH + h]);
        float f = fmaf(s6, w0[6 * NH + h], s7 * w0[7 * NH + h]);
        bp[h] += (a + c) + (e + f);
      }
    }
  }
#pragma unroll
  for (int h = 0; h < NH; ++h) red[dq][j][h] = bp[h];
  __syncthreads();

  // ---- combine partials + precomputed qk: this group's heads h = 2*dq + c ----
  float score[2], ex[2];
  {
    const float* sqk = Sqk + (((size_t)(b * NH + (dqu << 1)) * NTOK) + qi) * NTOK + j;
#pragma unroll
    for (int c = 0; c < 2; ++c) {
      int h = (dqu << 1) + c;
      float bias = (red[0][j][h] + red[1][j][h]) + (red[2][j][h] + red[3][j][h]);
      score[c] = sqk[(size_t)c * NTOK * NTOK] + bias;   // bb2 softmax-invariant
    }
  }

  // ---- softmax over j (4 waves per dq group) ----
#pragma unroll
  for (int c = 0; c < 2; ++c) {
    float m = score[c];
#pragma unroll
    for (int off = 32; off >= 1; off >>= 1) m = fmaxf(m, __shfl_xor(m, off));
    if (lane == 0) redm[dq][c][w4] = m;
  }
  __syncthreads();
#pragma unroll
  for (int c = 0; c < 2; ++c) {
    float m = fmaxf(fmaxf(redm[dq][c][0], redm[dq][c][1]),
                    fmaxf(redm[dq][c][2], redm[dq][c][3]));
    float e = __expf(score[c] - m);
    ex[c] = e;
    float s = e;
#pragma unroll
    for (int off = 32; off >= 1; off >>= 1) s += __shfl_xor(s, off);
    if (lane == 0) reds[dq][c][w4] = s;
  }
  __syncthreads();
  {
    float s0 = reds[dq][0][0] + reds[dq][0][1] + reds[dq][0][2] + reds[dq][0][3];
    float s1 = reds[dq][1][0] + reds[dq][1][1] + reds[dq][1][2] + reds[dq][1][3];
    float w0 = ex[0] * __builtin_amdgcn_rcpf(s0);
    float w1 = ex[1] * __builtin_amdgcn_rcpf(s1);
    // Wsm[q][h][j]: wave writes 256B contiguous per head row
    float* wo = Wsm + ((size_t)blk * NH + (dqu << 1)) * NTOK + j;
    wo[0] = w0;
    wo[NTOK] = w1;
    // stash w into red (free now; >=2 barriers since last red read)
    red[0][j][(dqu << 1) + 0] = w0;   // flat [j*9 + h]
    red[0][j][(dqu << 1) + 1] = w1;
  }
  __syncthreads();
  // ---- coalesced WsmT[q][j][0..7]: 32B/lane contiguous ----
  if (t < NTOK) {
    float4 wa = make_float4(red[0][t][0], red[0][t][1], red[0][t][2], red[0][t][3]);
    float4 wb = make_float4(red[0][t][4], red[0][t][5], red[0][t][6], red[0][t][7]);
    float4* wt = (float4*)(WsmT + (size_t)blk * (NH * NTOK) + t * NH);
    wt[0] = wa;
    wt[1] = wb;
  }
}

// ---------------- g_accum: g[q][h][d] = sum_j w[q][h][j] * silu(Sv[q,d]-Pv[j,d]) ----
// One block per (query, d-half). 256 threads, no LDS. Weights via uniform s_loads.
__global__ __launch_bounds__(256) void g_accum(
    const float* __restrict__ Sv, const ushort16* __restrict__ PvQ,
    const float* __restrict__ WsmT, ushort16* __restrict__ Gbf) {
  int t = threadIdx.x;
  // bijective XCD swizzle over 1024 blocks: XCD k gets 64 contiguous queries
  int lin = ((blockIdx.x & 7) << 7) + (blockIdx.x >> 3);
  int q = lin >> 1;
  int half = lin & 1;
  int b = q >> 8;
  int d = (half << 8) + t;
  float sv = Sv[(size_t)q * DM + d];
  const float* wt = WsmT + (size_t)q * (NH * NTOK);   // uniform -> s_load
  const ushort16* pq = PvQ + (size_t)(b * 64) * PVQ_STRIDE + d * 4;
  float g[NH];
#pragma unroll
  for (int h = 0; h < NH; ++h) g[h] = 0.f;
#pragma unroll 2
  for (int jq = 0; jq < 64; ++jq) {
    uint2 pk = *(const uint2*)(pq + (size_t)jq * PVQ_STRIDE);  // 4 bf16 (4 j's)
    float s0 = fast_silu(sv - bf16_lo(pk.x));
    float s1 = fast_silu(sv - bf16_hi(pk.x));
    float s2 = fast_silu(sv - bf16_lo(pk.y));
    float s3 = fast_silu(sv - bf16_hi(pk.y));
    const float* w0 = wt + (jq * 4) * NH;
#pragma unroll
    for (int h = 0; h < NH; ++h) g[h] = fmaf(s0, w0[h], g[h]);
#pragma unroll
    for (int h = 0; h < NH; ++h) g[h] = fmaf(s1, w0[NH + h], g[h]);
#pragma unroll
    for (int h = 0; h < NH; ++h) g[h] = fmaf(s2, w0[2 * NH + h], g[h]);
#pragma unroll
    for (int h = 0; h < NH; ++h) g[h] = fmaf(s3, w0[3 * NH + h], g[h]);
  }
#pragma unroll
  for (int h = 0; h < NH; ++h)
    Gbf[((size_t)q * NH + h) * DM + d] = bf16_rne(g[h]);
}

// ---------------- out GEMM: out = Wsm @ V + G @ Wv2^T + bv2, per head ----------------
// grid (16 i-tiles of 32, 8 heads), 256 thr, 32x64 tile, 2x4 micro.
__global__ __launch_bounds__(256) void out_gemm(
    const ushort16* __restrict__ Gbf, const float* __restrict__ Wsm,
    const float* __restrict__ Wv2, const float* __restrict__ V,
    const float* __restrict__ bv2, float* __restrict__ out) {
  __shared__ float As[32][33];
  __shared__ float Bs[64][33];
  int t = threadIdx.x;
  int bm = blockIdx.x;       // 32-query tile
  int h = blockIdx.y;        // head
  int tx = t & 15, ty = t >> 4;
  float acc[2][4] = {};

  // ---- GEMM1: G(32 x 512, bf16) @ Wv2_h^T(512 x 64), K-tile 32 ----
  {
    int lrA = t >> 3, lkA = (t & 7) * 4;
    int lrB = t >> 2, lkB = (t & 3) * 8;
    const ushort16* Ap = Gbf + ((size_t)(bm * 32 + lrA) * NH + h) * DM + lkA;
    const float* Bp = Wv2 + (size_t)(h * 64 + lrB) * DM + lkB;
    for (int k0 = 0; k0 < DM; k0 += 32) {
      uint2 ga = *(const uint2*)(Ap + k0);
      float4 w1 = *(const float4*)(Bp + k0);
      float4 w2 = *(const float4*)(Bp + k0 + 4);
      __syncthreads();
      As[lrA][lkA + 0] = bf16_lo(ga.x); As[lrA][lkA + 1] = bf16_hi(ga.x);
      As[lrA][lkA + 2] = bf16_lo(ga.y); As[lrA][lkA + 3] = bf16_hi(ga.y);
      Bs[lrB][lkB + 0] = w1.x; Bs[lrB][lkB + 1] = w1.y;
      Bs[lrB][lkB + 2] = w1.z; Bs[lrB][lkB + 3] = w1.w;
      Bs[lrB][lkB + 4] = w2.x; Bs[lrB][lkB + 5] = w2.y;
      Bs[lrB][lkB + 6] = w2.z; Bs[lrB][lkB + 7] = w2.w;
      __syncthreads();
#pragma unroll
      for (int kk = 0; kk < 32; ++kk) {
        float a0 = As[ty * 2 + 0][kk], a1 = As[ty * 2 + 1][kk];
        float b0 = Bs[tx * 4 + 0][kk], b1 = Bs[tx * 4 + 1][kk];
        float b2 = Bs[tx * 4 + 2][kk], b3 = Bs[tx * 4 + 3][kk];
        acc[0][0] = fmaf(a0, b0, acc[0][0]); acc[0][1] = fmaf(a0, b1, acc[0][1]);
        acc[0][2] = fmaf(a0, b2, acc[0][2]); acc[0][3] = fmaf(a0, b3, acc[0][3]);
        acc[1][0] = fmaf(a1, b0, acc[1][0]); acc[1][1] = fmaf(a1, b1, acc[1][1]);
        acc[1][2] = fmaf(a1, b2, acc[1][2]); acc[1][3] = fmaf(a1, b3, acc[1][3]);
      }
    }
  }

  // ---- GEMM2: Wsm(32 x 256) @ V(256 x 64), K-tile 32 ----
  {
    int lrA = t >> 3, lkA = (t & 7) * 4;
    int lrV = t >> 3, lcV = (t & 7) * 8;
    int b = bm >> 3;
    const float* A2p = Wsm + ((size_t)(bm * 32 + lrA) * NH + h) * NTOK + lkA;
    const float* Vp = V + ((size_t)(b * NH + h) * NTOK + lrV) * HDIM + lcV;
    float (*Vs)[65] = (float(*)[65])&Bs[0][0];   // 32x65 = 2080 <= 64x33
    for (int k0 = 0; k0 < NTOK; k0 += 32) {
      float4 a4 = *(const float4*)(A2p + k0);
      float4 v1 = *(const float4*)(Vp + (size_t)k0 * HDIM);
      float4 v2 = *(const float4*)(Vp + (size_t)k0 * HDIM + 4);
      __syncthreads();
      As[lrA][lkA + 0] = a4.x; As[lrA][lkA + 1] = a4.y;
      As[lrA][lkA + 2] = a4.z; As[lrA][lkA + 3] = a4.w;
      Vs[lrV][lcV + 0] = v1.x; Vs[lrV][lcV + 1] = v1.y;
      Vs[lrV][lcV + 2] = v1.z; Vs[lrV][lcV + 3] = v1.w;
      Vs[lrV][lcV + 4] = v2.x; Vs[lrV][lcV + 5] = v2.y;
      Vs[lrV][lcV + 6] = v2.z; Vs[lrV][lcV + 7] = v2.w;
      __syncthreads();
#pragma unroll
      for (int kk = 0; kk < 32; ++kk) {
        float a0 = As[ty * 2 + 0][kk], a1 = As[ty * 2 + 1][kk];
        float b0 = Vs[kk][tx * 4 + 0], b1 = Vs[kk][tx * 4 + 1];
        float b2 = Vs[kk][tx * 4 + 2], b3 = Vs[kk][tx * 4 + 3];
        acc[0][0] = fmaf(a0, b0, acc[0][0]); acc[0][1] = fmaf(a0, b1, acc[0][1]);
        acc[0][2] = fmaf(a0, b2, acc[0][2]); acc[0][3] = fmaf(a0, b3, acc[0][3]);
        acc[1][0] = fmaf(a1, b0, acc[1][0]); acc[1][1] = fmaf(a1, b1, acc[1][1]);
        acc[1][2] = fmaf(a1, b2, acc[1][2]); acc[1][3] = fmaf(a1, b3, acc[1][3]);
      }
    }
  }

  // ---- epilogue ----
  int o0 = h * 64 + tx * 4;
  float4 bvq = *(const float4*)(bv2 + o0);
#pragma unroll
  for (int r = 0; r < 2; ++r) {
    int bi = bm * 32 + ty * 2 + r;
    float4 res;
    res.x = acc[r][0] + bvq.x;
    res.y = acc[r][1] + bvq.y;
    res.z = acc[r][2] + bvq.z;
    res.w = acc[r][3] + bvq.w;
    *(float4*)&out[(size_t)bi * DM + o0] = res;
  }
}

extern "C" void kernel_launch(void* const* d_in, const int* in_sizes, int n_in,
                              void* d_out, int out_size, void* d_ws, size_t ws_size,
                              hipStream_t stream) {
  const float* x      = (const float*)d_in[0];
  const float* coords = (const float*)d_in[1];
  const float* Wqkv   = (const float*)d_in[2];
  const float* bqkv   = (const float*)d_in[3];
  const float* Wb1    = (const float*)d_in[4];
  const float* bb1    = (const float*)d_in[5];
  const float* Wb2    = (const float*)d_in[6];
  // d_in[7] = bb2: softmax-invariant, unused
  const float* Wv1    = (const float*)d_in[8];
  const float* bv1    = (const float*)d_in[9];
  const float* Wv2    = (const float*)d_in[10];
  const float* bv2    = (const float*)d_in[11];
  float* outp = (float*)d_out;
  float* ws = (float*)d_ws;

  const size_t SZ = (size_t)BATCH * NTOK * DM;             // 262144 floats
  const size_t WSM_SZ = (size_t)BATCH * NTOK * NH * NTOK;  // 1048576 floats
  const size_t PBT_SZ = (size_t)BATCH * 64 * PBT_STRIDE;   // ushorts
  const size_t PVQ_SZ = (size_t)BATCH * 64 * PVQ_STRIDE;   // ushorts
  float* Qw    = ws;
  float* Kw    = ws + SZ;
  float* Sbw   = ws + 2 * SZ;
  float* Svw   = ws + 3 * SZ;
  float* Vw    = ws + 4 * SZ;
  float* Wb2T  = ws + 5 * SZ;                        // 4096 floats
  float* Wsm   = ws + 5 * SZ + 4096;                 // [q][h][j]
  float* WsmT  = Wsm + WSM_SZ;                       // [q][j][h]
  ushort16* Gbf  = (ushort16*)(WsmT + WSM_SZ);       // [q][h][d] bf16 (WSM_SZ/2 floats)
  ushort16* PbT8 = (ushort16*)(WsmT + 2 * WSM_SZ);
  ushort16* PvQ  = PbT8 + PBT_SZ;
  float* Sqk   = (float*)(PvQ + PVQ_SZ) + 16;        // [b][h][i][j], 1 MB floats

  hipLaunchKernelGGL(prep_pe, dim3((BATCH * NTOK * DM) / 256), dim3(256), 0, stream,
                     coords, Wb1, bb1, Wv1, bv1, Wb2,
                     Sbw, Svw, PbT8, PvQ, Wb2T);
  hipLaunchKernelGGL(qkv_gemm, dim3(8, 24), dim3(256), 0, stream,
                     x, Wqkv, bqkv, Qw, Kw, Vw);
  hipLaunchKernelGGL(qk_gemm, dim3(16, BATCH * NH), dim3(256), 0, stream,
                     Qw, Kw, Sqk);
  hipLaunchKernelGGL(attn_score, dim3(BATCH * NTOK), dim3(1024), 0, stream,
                     Sqk, Sbw, PbT8, Wb2T, Wsm, WsmT);
  hipLaunchKernelGGL(g_accum, dim3(BATCH * NTOK * 2), dim3(256), 0, stream,
                     Svw, PvQ, WsmT, Gbf);
  hipLaunchKernelGGL(out_gemm, dim3(16, 8), dim3(256), 0, stream,
                     Gbf, Wsm, Wv2, Vw, bv2, outp);
}